// Round 11
// baseline (165.709 us; speedup 1.0000x reference)
//
#include <hip/hip_runtime.h>
#include <math.h>

#define NN 200000
#define DD 64
#define BB 4096
#define KK 128
#define WW 20
#define HH 128
#define TPB 512
#define RPB 4    // targets per block; 8 waves = 2 waves per target

#define INV2PI 0.15915494309189535f

__device__ __forceinline__ float fast_rcp(float x) { return __builtin_amdgcn_rcpf(x); }
__device__ __forceinline__ float fast_rsq(float x) { return __builtin_amdgcn_rsqf(x); }

// Round 11 = verified R6 (42.7 us, 28 VGPR, TPB=512) + the two R4 deltas that
// never got a fair measurement (R4: infra fail; R5: machine with broken HBM):
//   1. hist tap-split across waves 4-7 (2 threads/column x 10 taps) -- halves
//      the barrier-A straggler (waves 6-7 no longer serialize 20 HBM taps +
//      full part A); partials combined by threads 0-127 after barrier C.
//   2. GEMM 2h x 2row remap -- each tile b128 broadcast feeds 8 FMAs, LDS
//      reads halve (64->32/thread), 4 independent accumulator chains.
// Everything else verbatim R6 (bounded v_mul+v_cos everywhere, unroll-4
// part A, phase-3 uniform b128 broadcasts, W straight from L2).
// 1024 blocks x 512 threads, 4 targets/block, 6 block barriers.
__global__ __launch_bounds__(512, 8) void fused(
    const float* __restrict__ adj_time, const float* __restrict__ gc,
    const float* __restrict__ cur_time, const float* __restrict__ neigh_mask,
    const float* __restrict__ hist_feat, const float* __restrict__ hist_time,
    const float* __restrict__ t2v_w, const float* __restrict__ t2v_b,
    const float* __restrict__ node_w, const float* __restrict__ node_b,
    const float* __restrict__ att_w, const float* __restrict__ att_b,
    const float* __restrict__ weight,
    const int* __restrict__ targets, const int* __restrict__ neigh_idx,
    float* __restrict__ out)
{
    const int b0   = blockIdx.x * RPB;
    const int tid  = threadIdx.x;
    const int lane = tid & 63;
    const int wv   = tid >> 6;          // wave id 0..7

    __shared__ float4 dtg[RPB * KK];    // {dt, g, wk, -}; reused as prow     8 KB
    __shared__ float  stL[RPB];         // target att-dot per row
    __shared__ float  p3p[RPB][DD];     // phase-3 odd-wave partials           1 KB
    __shared__ float  tile[RPB * 256];  // feat4 rows                          4 KB
    __shared__ float4 hp[128];          // hist tap-half-1 partials            2 KB

    const float t = cur_time[0];

    // ---- gathers: one slot per thread (slot = r*128 + k = tid) ----
    const int   slot = tid;
    const int   idx  = neigh_idx[b0 * KK + slot];
    const float m    = neigh_mask[b0 * KK + slot];
    const float at   = adj_time[idx];
    const float g    = gc[idx];
    const float dt   = fabsf(t - at);
    const float ts   = fast_rcp(2.0f * __logf(2.71828182845904523536f + (t - at)));
    dtg[slot] = make_float4(dt, g, 0.f, 0.f);

    // ---- history aggregation, waves 4-7, tap-split (2 threads/column) ----
    if (tid >= 256) {
        const int i   = tid - 256;       // 0..255
        const int col = i >> 1;          // 0..127
        const int th  = i & 1;           // tap half: 0 -> taps 0-9, 1 -> 10-19
        const int r   = col >> 5;        // target row 0..3
        const int c4  = col & 31;        // float4 column
        const float*  ht = hist_time + (size_t)(b0 + r) * WW + th * 10;
        const float4* hf = (const float4*)(hist_feat + (size_t)(b0 + r) * WW * 128)
                         + c4 + th * 10 * 32;
        float4 s4 = make_float4(0.f, 0.f, 0.f, 0.f);
#pragma unroll
        for (int w = 0; w < 10; ++w) {
            float  hw = fast_rcp(2.0f * (1.0f + (t - ht[w])));
            float4 v  = hf[w * 32];
            s4.x = fmaf(hw, v.x, s4.x);
            s4.y = fmaf(hw, v.y, s4.y);
            s4.z = fmaf(hw, v.z, s4.z);
            s4.w = fmaf(hw, v.w, s4.w);
        }
        if (th == 0) *(float4*)(tile + r * 256 + c4 * 4) = s4;
        else         hp[col] = s4;
    }

    // ---- target encoding, wave wv -> target wv (waves 0-3) ----
    if (wv < RPB) {
        int   tg  = targets[b0 + wv];
        float dtT = fabsf(t - adj_time[tg]);
        float gT  = gc[tg];
        float ph  = fmaf(t2v_w[lane], dtT, t2v_b[lane]);
        float cv  = __builtin_amdgcn_cosf(ph * INV2PI);   // bounded v_mul+v_cos
        float tv_ = (lane == 0) ? ph : cv;
        float f   = fmaxf(tv_ + fmaf(gT, node_w[lane], node_b[lane]), 0.f);
        float ss  = f * f;
#pragma unroll
        for (int off = 32; off; off >>= 1) ss += __shfl_xor(ss, off, 64);
        float invn = fast_rsq(fmaxf(ss, 1e-24f));
        float tfn  = f * invn;
        float sdt  = tfn * att_w[lane];
#pragma unroll
        for (int off = 32; off; off >>= 1) sdt += __shfl_xor(sdt, off, 64);
        if (lane == 0) stL[wv] = sdt;
        tile[wv * 256 + 128 + lane] = tfn;
    }

    // ---- part A: 64-dim in-lane norm+att from registers (no LDS deps) ----
    float s2, sd;
    {
        {   // d = 0: linear channel (no cos)
            float ph = fmaf(t2v_w[0], dt, t2v_b[0]);
            float f  = fmaxf(ph + fmaf(g, node_w[0], node_b[0]), 0.f);
            s2 = f * f;
            sd = f * att_w[64];
        }
#pragma unroll 4
        for (int d = 1; d < 64; ++d) {
            float ph = fmaf(t2v_w[d], dt, t2v_b[d]);
            float cv = __builtin_amdgcn_cosf(ph * INV2PI);   // bounded v_mul+v_cos
            float f  = fmaxf(cv + fmaf(g, node_w[d], node_b[d]), 0.f);
            s2 = fmaf(f, f, s2);
            sd = fmaf(f, att_w[64 + d], sd);
        }
    }
    __syncthreads();   // A: stL, dtg.xy, hist tile/hp writes ready

    // ---- part B: finish score, write wk ----
    {
        float invn = fast_rsq(fmaxf(s2, 1e-24f));
        float sc   = ts + stL[slot >> 7] + sd * invn + att_b[0];
        sc = (sc > 0.f) ? sc : 0.01f * sc;          // leaky_relu(0.01)
        dtg[slot].z = sc * m * invn;                // packed wk
    }
    __syncthreads();   // C: wk ready

    // ---- hist tap-half combine (threads 0-127), overlapped with phase 3 ----
    if (tid < 128) {
        int r = tid >> 5, c4 = tid & 31;
        float4* tp = (float4*)(tile + r * 256 + c4 * 4);
        float4 a = *tp, b = hp[tid];
        *tp = make_float4(a.x + b.x, a.y + b.y, a.z + b.z, a.w + b.w);
    }

    // ---- phase 3: wave pair (2r, 2r+1) owns target r; lane = dim ----
    const int r3   = wv >> 1;
    const int half = wv & 1;
    float acc3 = 0.f;
    {
        float scn = (lane == 0) ? 1.f : INV2PI;     // lane 0 = linear channel
        float pw  = t2v_w[lane] * scn;
        float pb  = t2v_b[lane] * scn;
        float nw  = node_w[lane];
        float nb2 = node_b[lane];
        const int base = r3 * KK + half * 64;
#pragma unroll 4
        for (int k = 0; k < 64; ++k) {
            float4 dgw = dtg[base + k];             // uniform addr -> broadcast b128
            float  ph  = fmaf(pw, dgw.x, pb);
            float  cv  = __builtin_amdgcn_cosf(ph); // v_cos: cos(2*pi*ph)
            float  tv_ = lane ? cv : ph;
            float  f   = fmaxf(tv_ + fmaf(dgw.y, nw, nb2), 0.f);
            acc3 = fmaf(dgw.z, f, acc3);
        }
    }
    if (half) p3p[r3][lane] = acc3;
    __syncthreads();   // D: odd-wave partials ready
    if (!half) tile[r3 * 256 + 192 + lane] = acc3 + p3p[r3][lane];
    __syncthreads();   // E: tile complete; dtg dead

    // ---- GEMM: thread = (h2, sq, rh); 2 h x 2 rows in registers ----
    const int h2 = tid & 63;            // h and h+64
    const int sq = (tid >> 6) & 3;      // j-quarter 0..3
    const int rh = tid >> 8;            // row pair 0..1
    const float4* wA = (const float4*)weight + (h2     ) * 64 + sq * 16;
    const float4* wB = (const float4*)weight + (h2 + 64) * 64 + sq * 16;
    const float*  t0 = tile + (2 * rh    ) * 256 + sq * 64;
    const float*  t1 = tile + (2 * rh + 1) * 256 + sq * 64;
    float a00 = 0.f, a01 = 0.f, a10 = 0.f, a11 = 0.f;   // [row][h]
#pragma unroll 4
    for (int i = 0; i < 16; ++i) {
        float4 wa = wA[i];
        float4 wb = wB[i];
        float4 f0 = *(const float4*)(t0 + i * 4);   // uniform broadcasts
        float4 f1 = *(const float4*)(t1 + i * 4);
        a00 += wa.x * f0.x + wa.y * f0.y + wa.z * f0.z + wa.w * f0.w;
        a01 += wb.x * f0.x + wb.y * f0.y + wb.z * f0.z + wb.w * f0.w;
        a10 += wa.x * f1.x + wa.y * f1.y + wa.z * f1.z + wa.w * f1.w;
        a11 += wb.x * f1.x + wb.y * f1.y + wb.z * f1.z + wb.w * f1.w;
    }

    // ---- combine 4 sq-partials per (row, h) via dead dtg buffer ----
    float* prow = (float*)dtg;                      // 2048 floats
    prow[((2 * rh    ) * 4 + sq) * 128 + h2     ] = a00;
    prow[((2 * rh    ) * 4 + sq) * 128 + h2 + 64] = a01;
    prow[((2 * rh + 1) * 4 + sq) * 128 + h2     ] = a10;
    prow[((2 * rh + 1) * 4 + sq) * 128 + h2 + 64] = a11;
    __syncthreads();   // F
    {
        const int r2 = tid >> 7;
        const int h  = tid & 127;
        float s = prow[(r2 * 4 + 0) * 128 + h] + prow[(r2 * 4 + 1) * 128 + h]
                + prow[(r2 * 4 + 2) * 128 + h] + prow[(r2 * 4 + 3) * 128 + h];
        out[(size_t)(b0 + r2) * 128 + h] = fmaxf(s, 0.f);
    }
}

extern "C" void kernel_launch(void* const* d_in, const int* in_sizes, int n_in,
                              void* d_out, int out_size, void* d_ws, size_t ws_size,
                              hipStream_t stream) {
    const float* adj_time  = (const float*)d_in[0];
    const float* gc        = (const float*)d_in[1];
    const float* cur_time  = (const float*)d_in[2];
    const float* neigh_mask= (const float*)d_in[3];
    const float* hist_feat = (const float*)d_in[4];
    const float* hist_time = (const float*)d_in[5];
    const float* t2v_w     = (const float*)d_in[6];
    const float* t2v_b     = (const float*)d_in[7];
    const float* node_w    = (const float*)d_in[8];
    const float* node_b    = (const float*)d_in[9];
    const float* att_w     = (const float*)d_in[10];
    const float* att_b     = (const float*)d_in[11];
    const float* weight    = (const float*)d_in[12];
    const int*   targets   = (const int*)d_in[13];
    const int*   neigh_idx = (const int*)d_in[14];

    float* out = (float*)d_out;

    fused<<<BB / RPB, TPB, 0, stream>>>(adj_time, gc, cur_time, neigh_mask,
                                        hist_feat, hist_time, t2v_w, t2v_b,
                                        node_w, node_b, att_w, att_b, weight,
                                        targets, neigh_idx, out);
}

// Round 13
// 135.339 us; speedup vs baseline: 1.2244x; 1.2244x over previous
//
#include <hip/hip_runtime.h>
#include <math.h>

#define NN 200000
#define DD 64
#define BB 4096
#define KK 128
#define WW 20
#define HH 128
#define TPB 512
#define RPB 8    // targets per block

__device__ __forceinline__ float fast_rcp(float x) { return __builtin_amdgcn_rcpf(x); }
__device__ __forceinline__ float fast_rsq(float x) { return __builtin_amdgcn_rsqf(x); }

// FINAL: pure revert to the session's best-verified kernel (round-0 baseline;
// fused dispatch 42.0-42.4 us across 3 profiled dispatches, JSON 134.6 us).
// 11 controlled experiments (occupancy 16<->32 waves, LDS traffic 4x down,
// barriers 21->5, bounded-cos, register-resident dedup core, sync-domain
// halving, phase-balance + GEMM-ILP) all landed at >= this kernel's wall;
// VALU busy-time tracked instruction count (16.5-23 us) but the wall never
// followed. No counter shows a saturated pipe (VALU ~50%, HBM ~10%,
// conflicts ~0, no spill): the ~42 us floor is a correlated-stall property
// of this op's 7-phase dependency structure, and this geometry is its
// best-measured point. (Round-12 submission of this exact source hit an
// infra failure -- "container failed twice", no compile/pytest output --
// resubmitted verbatim.)
//
// Fully-fused pipeline: 512 blocks x 512 threads, 8 targets/block (2
// blocks/CU, single occupancy round). Per block:
//   pre-A : gathers (2 slots/thread), hws, per-wave target encodings (wave w =
//           target w; tgt_feat written straight into the LDS feat4 tile).
//   phase1: thread computes full 64-dim feature norm+att-dot for its 2 slots
//           in-lane (params via uniform s_loads) and writes wk[slot] directly.
//   hist  : 2 (r,d) columns/thread, 20-tap decay FMA into tile cols 0-127.
//   phase3: wave w re-computes features for target w's 128 neighbors
//           (lane=dim), FMA-accumulates into tile cols 192-255.
//   GEMM  : relu(tile @ W^T) with W staged chunk-wise in LDS (pad-33).
// feat4 never touches HBM; no second launch.
__global__ __launch_bounds__(512, 4) void fused(
    const float* __restrict__ adj_time, const float* __restrict__ gc,
    const float* __restrict__ cur_time, const float* __restrict__ neigh_mask,
    const float* __restrict__ hist_feat, const float* __restrict__ hist_time,
    const float* __restrict__ t2v_w, const float* __restrict__ t2v_b,
    const float* __restrict__ node_w, const float* __restrict__ node_b,
    const float* __restrict__ att_w, const float* __restrict__ att_b,
    const float* __restrict__ weight,
    const int* __restrict__ targets, const int* __restrict__ neigh_idx,
    float* __restrict__ out)
{
    const int b0   = blockIdx.x * RPB;
    const int tid  = threadIdx.x;
    const int lane = tid & 63;
    const int wv   = tid >> 6;          // wave id 0..7 == target row

    __shared__ float2 dtg[RPB * KK];    // {dt, g} per (target, neighbor)   8 KB
    __shared__ float  wk[RPB * KK];     // per-neighbor weight              4 KB
    __shared__ float  hws[RPB][WW];     // history decay weights          640 B
    __shared__ float  stL[RPB];         // target att-dot per row
    __shared__ float  tile[RPB * 256];  // feat4 rows                       8 KB
    __shared__ float  wl[128 * 33];     // W chunk [128 h][32 j], pad 33   ~17 KB

    const float t = cur_time[0];

    // ---- pre-A: gathers (2 slots/thread) ----
    float ts_r[2], m_r[2];
#pragma unroll
    for (int i = 0; i < 2; ++i) {
        int   slot = tid + i * TPB;                 // slot = r*128 + k
        int   idx  = neigh_idx[b0 * KK + slot];
        m_r[i]     = neigh_mask[b0 * KK + slot];
        float at   = adj_time[idx];
        float g    = gc[idx];
        dtg[slot]  = make_float2(fabsf(t - at), g);
        ts_r[i]    = fast_rcp(2.0f * __logf(2.71828182845904523536f + (t - at)));
    }
    // ---- pre-A: history decay weights ----
    if (tid < RPB * WW) {
        int r = tid / WW, w = tid - r * WW;
        hws[r][w] = fast_rcp(2.0f * (1.0f + (t - hist_time[(b0 + r) * WW + w])));
    }
    // ---- pre-A: target encoding, wave wv -> target wv ----
    {
        int   tg  = targets[b0 + wv];
        float dtT = fabsf(t - adj_time[tg]);
        float gT  = gc[tg];
        float ph  = fmaf(t2v_w[lane], dtT, t2v_b[lane]);
        float tv_ = (lane == 0) ? ph : __cosf(ph);
        float f   = fmaxf(tv_ + fmaf(gT, node_w[lane], node_b[lane]), 0.f);
        float ss  = f * f;
#pragma unroll
        for (int off = 32; off; off >>= 1) ss += __shfl_xor(ss, off, 64);
        float invn = fast_rsq(fmaxf(ss, 1e-24f));
        float tfn  = f * invn;
        float sdt  = tfn * att_w[lane];
#pragma unroll
        for (int off = 32; off; off >>= 1) sdt += __shfl_xor(sdt, off, 64);
        if (lane == 0) stL[wv] = sdt;
        tile[wv * 256 + 128 + lane] = tfn;
    }
    __syncthreads();   // A: dtg, hws, stL ready

    // ---- phase 1: full 64-dim in-lane per slot; params via literal-offset s_loads ----
    const float ab = att_b[0];
#pragma unroll
    for (int i = 0; i < 2; ++i) {
        int    slot = tid + i * TPB;
        int    r    = slot >> 7;
        float2 dg   = dtg[slot];
        float  s2 = 0.f, sd = 0.f;
#pragma unroll 8
        for (int d = 0; d < 64; ++d) {
            float ph  = fmaf(t2v_w[d], dg.x, t2v_b[d]);
            float cv  = __cosf(ph);
            float tv_ = (d == 0) ? ph : cv;
            float f   = fmaxf(tv_ + fmaf(dg.y, node_w[d], node_b[d]), 0.f);
            s2 = fmaf(f, f, s2);
            sd = fmaf(f, att_w[64 + d], sd);
        }
        float invn = fast_rsq(fmaxf(s2, 1e-24f));
        float sc   = ts_r[i] + stL[r] + sd * invn + ab;
        sc = (sc > 0.f) ? sc : 0.01f * sc;          // leaky_relu(0.01)
        wk[slot] = sc * m_r[i] * invn;
    }

    // ---- history aggregation into tile cols 0-127 (2 columns/thread) ----
#pragma unroll
    for (int i = 0; i < 2; ++i) {
        int col = tid + i * TPB;
        int r = col >> 7, d = col & 127;
        const float* hf = hist_feat + (size_t)(b0 + r) * WW * 128 + d;
        float s = 0.f;
#pragma unroll
        for (int w = 0; w < WW; ++w) s = fmaf(hws[r][w], hf[w * 128], s);
        tile[r * 256 + d] = s;
    }
    __syncthreads();   // C: wk ready

    // ---- phase 3: wave wv owns target wv; lane = dim; recompute + FMA ----
    {
        float pw = t2v_w[lane], pb = t2v_b[lane];
        float nw = node_w[lane], nb2 = node_b[lane];
        float acc = 0.f;
        const int base = wv * KK;
#pragma unroll 8
        for (int k = 0; k < KK; ++k) {
            float2 dg = dtg[base + k];              // uniform addr -> broadcast
            float  w_ = wk[base + k];
            float  ph = fmaf(pw, dg.x, pb);
            float  cv = __cosf(ph);
            float  tv_ = (lane == 0) ? ph : cv;
            float  f  = fmaxf(tv_ + fmaf(dg.y, nw, nb2), 0.f);
            acc = fmaf(w_, f, acc);
        }
        tile[wv * 256 + 192 + lane] = acc;
    }

    // ---- GEMM: out = relu(tile @ W^T); thread = (h, g), 2 targets/thread ----
    const int h = tid & 127;
    const int g = tid >> 7;                         // 0..3 -> rows {2g, 2g+1}
    const float* tb = tile + (g * 2) * 256;
    float acc0 = 0.f, acc1 = 0.f;

    for (int c = 0; c < 8; ++c) {
        __syncthreads();   // c=0: covers phase-3/hist tile writes; else: wl reuse
#pragma unroll
        for (int i = 0; i < 8; ++i) {
            int l  = i * TPB + tid;
            int hh = l >> 5, jj = l & 31;
            wl[hh * 33 + jj] = weight[hh * 256 + c * 32 + jj];
        }
        __syncthreads();

#pragma unroll
        for (int jj = 0; jj < 32; jj += 4) {
            float w0 = wl[h * 33 + jj + 0];
            float w1 = wl[h * 33 + jj + 1];
            float w2 = wl[h * 33 + jj + 2];
            float w3 = wl[h * 33 + jj + 3];
            float4 f0 = *(const float4*)(tb + 0 * 256 + c * 32 + jj);
            float4 f1 = *(const float4*)(tb + 1 * 256 + c * 32 + jj);
            acc0 += w0 * f0.x + w1 * f0.y + w2 * f0.z + w3 * f0.w;
            acc1 += w0 * f1.x + w1 * f1.y + w2 * f1.z + w3 * f1.w;
        }
    }

    out[(size_t)(b0 + g * 2 + 0) * 128 + h] = fmaxf(acc0, 0.f);
    out[(size_t)(b0 + g * 2 + 1) * 128 + h] = fmaxf(acc1, 0.f);
}

extern "C" void kernel_launch(void* const* d_in, const int* in_sizes, int n_in,
                              void* d_out, int out_size, void* d_ws, size_t ws_size,
                              hipStream_t stream) {
    const float* adj_time  = (const float*)d_in[0];
    const float* gc        = (const float*)d_in[1];
    const float* cur_time  = (const float*)d_in[2];
    const float* neigh_mask= (const float*)d_in[3];
    const float* hist_feat = (const float*)d_in[4];
    const float* hist_time = (const float*)d_in[5];
    const float* t2v_w     = (const float*)d_in[6];
    const float* t2v_b     = (const float*)d_in[7];
    const float* node_w    = (const float*)d_in[8];
    const float* node_b    = (const float*)d_in[9];
    const float* att_w     = (const float*)d_in[10];
    const float* att_b     = (const float*)d_in[11];
    const float* weight    = (const float*)d_in[12];
    const int*   targets   = (const int*)d_in[13];
    const int*   neigh_idx = (const int*)d_in[14];

    float* out = (float*)d_out;

    fused<<<BB / RPB, TPB, 0, stream>>>(adj_time, gc, cur_time, neigh_mask,
                                        hist_feat, hist_time, t2v_w, t2v_b,
                                        node_w, node_b, att_w, att_b, weight,
                                        targets, neigh_idx, out);
}